// Round 5
// baseline (614.697 us; speedup 1.0000x reference)
//
#include <hip/hip_runtime.h>
#include <cstdint>
#include <cstddef>

// Problem constants
#define NB 512
#define NR 1152
#define NC 8
#define NJ 10
#define NO 16
#define NJO 160   // NJ*NO

// Fused-pass tiling
#define BT 32          // b per block
#define RC 64          // r per block
#define SR 4           // r per slice
#define NSL (RC / SR)  // 16 slices
#define UP 84          // padded u-row stride in u32 (80 used; 84 = 4-aligned, odd/32 bank spread)

typedef unsigned int uint32;

// ---- bf16 helpers ----
__device__ __forceinline__ uint32 f2bf(float f) {
    uint32 x = __float_as_uint(f);
    return (x + 0x7fffu + ((x >> 16) & 1u)) >> 16;
}
__device__ __forceinline__ float bflo(uint32 w) { return __uint_as_float(w << 16); }
__device__ __forceinline__ float bfhi(uint32 w) { return __uint_as_float(w & 0xffff0000u); }
// pack two floats to bf16 pair (round-to-nearest, ties away) in 3 ops via v_perm
__device__ __forceinline__ uint32 packbf(float a0, float a1) {
    uint32 u0 = __float_as_uint(a0) + 0x8000u;
    uint32 u1 = __float_as_uint(a1) + 0x8000u;
    return __builtin_amdgcn_perm(u1, u0, 0x07060302u);  // [u0.hi16 | u1.hi16<<16]
}

// ============================================================================
// Fused routing pass. Grid (NR/RC=18, NB/BT=16), block 256.
// Per slice of SR=4 r's:
//   A : u-tile[rr][b][p] = bf16pair(W[r]·x[b,r]) built in LDS (W in regs,
//       balanced (col, b-quad) unit assignment: 2560 units = 10/thread)
//   B1: b_ij = u-row · vsum(bf16), softmax over j -> cs (skipped if UNIFORM)
//   B2: acc[20] += c_j * u  (thread owns (b, 20-jo slice); regs across slices)
// End: 20 global atomicAdds per thread into s (18 blocks add per address).
// u_hat is NEVER materialized in global memory.
// ============================================================================
template <bool UNIFORM>
__global__ __launch_bounds__(256, 2) void fused_pass(const float* __restrict__ x,
                                                     const float* __restrict__ W,
                                                     const uint32* __restrict__ vsb,
                                                     float* __restrict__ s) {
    const int rc0 = blockIdx.x * RC;
    const int b0  = blockIdx.y * BT;
    const int t   = threadIdx.x;

    __shared__ uint32 us[SR * BT * UP];   // u-tile, bf16 pairs, stride UP
    __shared__ float  xs[SR][BT][NC];     // x-tile
    __shared__ float  cs[SR][BT][12];     // softmax coeffs (10 used)
    __shared__ uint32 vs[BT * UP];        // vsum bf16 pairs, stride UP

    if (!UNIFORM) {
        for (int i = t; i < BT * 80; i += 256)
            vs[(i / 80) * UP + (i % 80)] = vsb[b0 * 80 + i];
    }

    // B2 ownership: thread = (b = t>>3, oct = t&7) -> jo in [20*oct, 20*oct+20)
    const int ab    = t >> 3;
    const int oct   = t & 7;
    const int p0    = 10 * oct;              // first u32-pair of this jo range
    const int j0    = (5 * oct) >> 2;        // first j in range (spans exactly 2 j's)
    const int istar = 16 - 4 * (oct & 3);    // i < istar -> j0, else j0+1
    float acc[20];
#pragma unroll
    for (int i = 0; i < 20; ++i) acc[i] = 0.0f;

#pragma unroll 1
    for (int sl = 0; sl < NSL; ++sl) {
        const int rbase = rc0 + sl * SR;

        __syncthreads();   // prev slice's B readers done with us/cs
        // stage xs: exactly 256 float4s: t -> (rr = t>>6, b = (t>>1)&31, h = t&1)
        {
            int rr = t >> 6, b = (t >> 1) & 31, h = t & 1;
            float4 v = *(const float4*)&x[(size_t)(b0 + b) * (NR * NC) +
                                          (size_t)(rbase + rr) * NC + h * 4];
            *(float4*)&xs[rr][b][h * 4] = v;
        }
        __syncthreads();

        // ---- Phase A: build u-tile. 320 cols (rr,p) x 8 b-quads = 2560 units.
        {
            int col = -1, rr = 0;
            uint32* urow = nullptr;
            float w[16];
#pragma unroll 1
            for (int k = 0; k < 10; ++k) {
                int unit = 10 * t + k;
                int c2 = unit >> 3, bq = unit & 7;
                if (c2 != col) {
                    col = c2;
                    rr = col / 80;
                    int p = col - 80 * rr;
                    const float4* wp =
                        (const float4*)&W[(size_t)(rbase + rr) * (NJO * NC) + p * 16];
                    float4 w0 = wp[0], w1 = wp[1], w2 = wp[2], w3 = wp[3];
                    w[0]=w0.x;  w[1]=w0.y;  w[2]=w0.z;  w[3]=w0.w;
                    w[4]=w1.x;  w[5]=w1.y;  w[6]=w1.z;  w[7]=w1.w;
                    w[8]=w2.x;  w[9]=w2.y;  w[10]=w2.z; w[11]=w2.w;
                    w[12]=w3.x; w[13]=w3.y; w[14]=w3.z; w[15]=w3.w;
                    urow = &us[rr * BT * UP + p];
                }
#pragma unroll
                for (int i = 0; i < 4; ++i) {
                    int bb = 4 * bq + i;
                    const float4* xp = (const float4*)&xs[rr][bb][0];
                    float4 xa = xp[0], xb = xp[1];
                    float a0 = w[0]*xa.x + w[1]*xa.y + w[2]*xa.z + w[3]*xa.w
                             + w[4]*xb.x + w[5]*xb.y + w[6]*xb.z + w[7]*xb.w;
                    float a1 = w[8]*xa.x + w[9]*xa.y + w[10]*xa.z + w[11]*xa.w
                             + w[12]*xb.x + w[13]*xb.y + w[14]*xb.z + w[15]*xb.w;
                    urow[bb * UP] = packbf(a0, a1);
                }
            }
        }
        __syncthreads();

        // ---- Phase B1: dot + softmax -> cs. 128 items = (rr = t>>5, b = t&31).
        if (!UNIFORM) {
            if (t < SR * BT) {
                int rr = t >> 5, b = t & 31;
                const uint4* up = (const uint4*)&us[(rr * BT + b) * UP];
                const uint4* vp = (const uint4*)&vs[b * UP];
                float ej[NJ];
                float sum = 0.0f;
#pragma unroll
                for (int j = 0; j < NJ; ++j) {
                    uint4 ua = up[2 * j], ub = up[2 * j + 1];
                    uint4 va = vp[2 * j], vb = vp[2 * j + 1];
                    float bj =
                        bflo(ua.x)*bflo(va.x) + bfhi(ua.x)*bfhi(va.x) +
                        bflo(ua.y)*bflo(va.y) + bfhi(ua.y)*bfhi(va.y) +
                        bflo(ua.z)*bflo(va.z) + bfhi(ua.z)*bfhi(va.z) +
                        bflo(ua.w)*bflo(va.w) + bfhi(ua.w)*bfhi(va.w) +
                        bflo(ub.x)*bflo(vb.x) + bfhi(ub.x)*bfhi(vb.x) +
                        bflo(ub.y)*bflo(vb.y) + bfhi(ub.y)*bfhi(vb.y) +
                        bflo(ub.z)*bflo(vb.z) + bfhi(ub.z)*bfhi(vb.z) +
                        bflo(ub.w)*bflo(vb.w) + bfhi(ub.w)*bfhi(vb.w);
                    float e = __expf(bj);   // |bj| <~ 25, safe without max-sub
                    ej[j] = e;
                    sum += e;
                }
                float inv = 1.0f / sum;
#pragma unroll
                for (int j = 0; j < NJ; ++j) cs[rr][b][j] = ej[j] * inv;
            }
            __syncthreads();
        }

        // ---- Phase B2: acc += c * u over this slice's SR r's.
        {
            const uint32* ub = &us[ab * UP + p0];
#pragma unroll
            for (int rr = 0; rr < SR; ++rr) {
                float c0, c1;
                if (UNIFORM) { c0 = 0.1f; c1 = 0.1f; }
                else { c0 = cs[rr][ab][j0]; c1 = cs[rr][ab][j0 + 1]; }
                const uint32* u = ub + rr * BT * UP;
#pragma unroll
                for (int q = 0; q < 10; ++q) {
                    uint32 uu = u[q];
                    float cA = (2 * q     < istar) ? c0 : c1;
                    float cB = (2 * q + 1 < istar) ? c0 : c1;
                    acc[2 * q]     += cA * bflo(uu);
                    acc[2 * q + 1] += cB * bfhi(uu);
                }
            }
        }
    }

    // global combine: 18 r-chunk blocks add per address
    float* sp = &s[(size_t)(b0 + ab) * NJO + 20 * oct];
#pragma unroll
    for (int i = 0; i < 20; ++i) atomicAdd(&sp[i], acc[i]);
}

// ============================================================================
// Squash: v = (sq/(1+sq)) * s * rsqrt(sq+1e-8), sq = ||s_j||^2 (16-lane shfl).
// MODE 0: vacc += v, pack bf16 vsum for next pass. MODE 1: write out.
// ============================================================================
template <int MODE>
__global__ __launch_bounds__(256) void squash_kernel(const float* __restrict__ s,
                                                     float* __restrict__ vacc,
                                                     uint32* __restrict__ vsb,
                                                     float* __restrict__ outp) {
    const int idx = blockIdx.x * 256 + threadIdx.x;  // < 81920; idx%16 = o
    float val = s[idx];
    float sq = val * val;
#pragma unroll
    for (int off = 1; off < 16; off <<= 1) sq += __shfl_xor(sq, off, 16);
    float scale = (sq / (1.0f + sq)) * rsqrtf(sq + 1e-8f);
    float v = val * scale;
    if (MODE == 1) {
        outp[idx] = v;
    } else {
        float va = vacc[idx] + v;
        vacc[idx] = va;
        float vnext = __shfl_down(va, 1);
        if ((idx & 1) == 0) vsb[idx >> 1] = f2bf(va) | (f2bf(vnext) << 16);
    }
}

// ============================================================================
extern "C" void kernel_launch(void* const* d_in, const int* in_sizes, int n_in,
                              void* d_out, int out_size, void* d_ws, size_t ws_size,
                              hipStream_t stream) {
    (void)in_sizes; (void)n_in; (void)out_size; (void)ws_size;

    const float* x = (const float*)d_in[0];  // [B,R,C]
    const float* W = (const float*)d_in[1];  // [R,J,O,C]
    float* out = (float*)d_out;              // [B,J,O,1] fp32

    char* ws = (char*)d_ws;
    float*  s0   = (float*)ws;                 // [B,160]
    float*  s1   = s0 + NB * NJO;
    float*  s2   = s1 + NB * NJO;
    float*  vacc = s2 + NB * NJO;              // [B,160] fp32 running v-sum
    uint32* vsb  = (uint32*)(vacc + NB * NJO); // [B,80] bf16 pairs

    // zero s0,s1,s2,vacc (contiguous)
    hipMemsetAsync(s0, 0, (size_t)4 * NB * NJO * sizeof(float), stream);

    const dim3 fgrid(NR / RC, NB / BT);  // (18, 16)
    const int  sgrid = (NB * NJO) / 256; // 320

    // iter 0: c uniform (=1/10) -> s0 -> v0 (vacc=v0, vsb=bf16(v0))
    fused_pass<true><<<fgrid, 256, 0, stream>>>(x, W, vsb, s0);
    squash_kernel<0><<<sgrid, 256, 0, stream>>>(s0, vacc, vsb, nullptr);

    // iter 1: b1 = u.v0 -> s1 -> v1 (vacc=v0+v1, vsb updated)
    fused_pass<false><<<fgrid, 256, 0, stream>>>(x, W, vsb, s1);
    squash_kernel<0><<<sgrid, 256, 0, stream>>>(s1, vacc, vsb, nullptr);

    // iter 2: b2 = u.(v0+v1) -> s2 -> v2 = output
    fused_pass<false><<<fgrid, 256, 0, stream>>>(x, W, vsb, s2);
    squash_kernel<1><<<sgrid, 256, 0, stream>>>(s2, nullptr, nullptr, out);
}